// Round 18
// baseline (81.670 us; speedup 1.0000x reference)
//
#include <hip/hip_runtime.h>
#include <hip/hip_bf16.h>

// CosSim2D: inputs (32,64,64,64) f32, w (1,576,128) f32, p (128), q (1)
// out (32,64,64,128) f32.
// R18 = R17 (2-row blocks, 1024 grid, 32x32x16 MFMA, conflict-free 72-pad
// LDS, frag-contiguous B, fused fp32 norm, setprio MFMA cluster, NT
// line-complete scalar epilogue, register p-factors) + TWO-DEEP B prefetch
// (bc/bn/bt; step s issues loads for s+2 -> ~2 MFMA clusters cover L2
// latency) + p-factor expf hoisted above the MFMA loop.

typedef short bf16x8 __attribute__((ext_vector_type(8)));
typedef float f32x16 __attribute__((ext_vector_type(16)));

__device__ __forceinline__ unsigned short f2bf(float f) {
    union { float f; unsigned int u; } v; v.f = f;
    unsigned int u = v.u;
    unsigned int r = (u + 0x7fffu + ((u >> 16) & 1u)) >> 16;  // RNE
    return (unsigned short)r;
}

// ---- pre-kernel: normalize w columns (fp32), store bf16 fragment-contiguous:
// wn2[((tap*2 + kc)*128 + n)*32 + koff] = w_hat[k = tap*64 + kc*32 + koff][n]
__global__ void prep_w_kernel(const float* __restrict__ w,
                              unsigned short* __restrict__ wn2) {
    const int n = blockIdx.x;
    const int lane = threadIdx.x;
    float vals[9];
    float s = 0.f;
#pragma unroll
    for (int i = 0; i < 9; ++i) {
        float v = w[(i * 64 + lane) * 128 + n];
        vals[i] = v;
        s += v * v;
    }
#pragma unroll
    for (int off = 1; off < 64; off <<= 1) s += __shfl_xor(s, off);
    const float inv = 1.0f / sqrtf(fmaxf(s, 1e-12f));
    const int kc = lane >> 5, koff = lane & 31;
#pragma unroll
    for (int i = 0; i < 9; ++i)
        wn2[((i * 2 + kc) * 128 + n) * 32 + koff] = f2bf(vals[i] * inv);
}

// ---- main: one block = (image b, output rows y0,y0+1); 128 pixels x 128 n
__global__ __launch_bounds__(256, 4) void cossim_main(
    const float* __restrict__ in, const unsigned short* __restrict__ wn,
    const float* __restrict__ p, const float* __restrict__ q,
    float* __restrict__ out) {
    // A: [4 rows][66 cols (zero-pad 0,65)][72 ch (64 + 16B pad)] bf16 = 38016 B
    __shared__ unsigned short A[4 * 66 * 72];
    __shared__ float rcsum[256];   // per-(row,col) fp32 square-sums
    __shared__ float xni[128];     // per-pixel 1/(||x||+q_eff)

    const int tid = (int)threadIdx.x;
    // bijective XCD swizzle: 1024 blocks, 8 XCDs, 128 consecutive l per XCD
    const int l = ((int)blockIdx.x & 7) * 128 + ((int)blockIdx.x >> 3);
    const int b = l >> 5, y0 = (l & 31) * 2;

    // ---- stage 4 input rows (y0-1 .. y0+2) + fused fp32 norm partials
    {
        const int r = tid >> 6;        // staged row 0..3
        const int col = tid & 63;
        const int row = y0 + r - 1;
        unsigned short* dst = &A[(r * 66 + col + 1) * 72];
        float s = 0.f;
        if ((unsigned)row < 64u) {
            const float4* src = reinterpret_cast<const float4*>(
                in + (size_t)b * 262144 + row * 4096 + col * 64);
#pragma unroll
            for (int it = 0; it < 8; ++it) {
                float4 v0 = src[2 * it];
                float4 v1 = src[2 * it + 1];
                s += v0.x * v0.x + v0.y * v0.y + v0.z * v0.z + v0.w * v0.w;
                s += v1.x * v1.x + v1.y * v1.y + v1.z * v1.z + v1.w * v1.w;
                union { float f; unsigned u; } ux, uy, uz, uw;
                uint4 pk;
                ux.f = v0.x; uy.f = v0.y; uz.f = v0.z; uw.f = v0.w;
                pk.x = __builtin_amdgcn_perm(uy.u + 0x8000u, ux.u + 0x8000u, 0x07060302u);
                pk.y = __builtin_amdgcn_perm(uw.u + 0x8000u, uz.u + 0x8000u, 0x07060302u);
                ux.f = v1.x; uy.f = v1.y; uz.f = v1.z; uw.f = v1.w;
                pk.z = __builtin_amdgcn_perm(uy.u + 0x8000u, ux.u + 0x8000u, 0x07060302u);
                pk.w = __builtin_amdgcn_perm(uw.u + 0x8000u, uz.u + 0x8000u, 0x07060302u);
                *reinterpret_cast<uint4*>(dst + it * 8) = pk;
            }
        } else {
            uint4 z; z.x = z.y = z.z = z.w = 0u;
#pragma unroll
            for (int it = 0; it < 8; ++it)
                *reinterpret_cast<uint4*>(dst + it * 8) = z;
        }
        rcsum[tid] = s;
    }
    if (tid < 64) {  // zero border cols 0 and 65, all 4 rows
        const int r = tid >> 4, side = (tid >> 3) & 1, ch = (tid & 7) * 8;
        uint4 z; z.x = z.y = z.z = z.w = 0u;
        *reinterpret_cast<uint4*>(&A[(r * 66 + side * 65) * 72 + ch]) = z;
    }
    __syncthreads();

    // ---- per-pixel 1/(||x||+q_eff) from fp32 partials
    if (tid < 128) {
        const int ry = tid >> 6, x = tid & 63;
        const float qe = expf(q[0] * (-1.0f / 0.3f));
        float s = 0.f;
#pragma unroll
        for (int dy = 0; dy < 3; ++dy) {
            const float* rs = &rcsum[(ry + dy) * 64];
            if (x > 0) s += rs[x - 1];
            s += rs[x];
            if (x < 63) s += rs[x + 1];
        }
        xni[tid] = 1.0f / (sqrtf(fmaxf(s, 1e-12f)) + qe);
    }
    __syncthreads();   // xni ready -> epilogue needs NO barrier

    // ---- MFMA loop (32x32x16): wave = output-row wm, 64 px x 64 n (n-half
    // wnh) as 2x2 tiles of 32x32. Per step: 4 A ds_reads + 4 B loads + 8 MFMA.
    // A-frag: row = l&31, k = 8*(l>>5)+j. B-frag: col = l&31, same k.
    const int wv = tid >> 6, lane = tid & 63;
    const int ln31 = lane & 31, khi = lane >> 5;   // khi in {0,1}
    const int wm = wv >> 1, wnh = wv & 1;
    f32x16 acc00 = {}, acc01 = {}, acc10 = {}, acc11 = {};
    const unsigned short* wB = wn + (wnh * 64 + ln31) * 32 + khi * 8;

    // epilogue p-factors hoisted off the post-loop serial path
    const int n0 = wnh * 64 + ln31;
    const float pn0 = expf(p[n0] * 0.2f);
    const float pn1 = expf(p[n0 + 32] * 0.2f);

    // two-deep B pipeline: bc = step s, bn = s+1, bt = s+2 (issued in loop)
    bf16x8 bc00 = *reinterpret_cast<const bf16x8*>(wB);
    bf16x8 bc01 = *reinterpret_cast<const bf16x8*>(wB + 16);
    bf16x8 bc10 = *reinterpret_cast<const bf16x8*>(wB + 1024);
    bf16x8 bc11 = *reinterpret_cast<const bf16x8*>(wB + 1040);
    bf16x8 bn00 = *reinterpret_cast<const bf16x8*>(wB + 4096);
    bf16x8 bn01 = *reinterpret_cast<const bf16x8*>(wB + 4112);
    bf16x8 bn10 = *reinterpret_cast<const bf16x8*>(wB + 5120);
    bf16x8 bn11 = *reinterpret_cast<const bf16x8*>(wB + 5136);

#pragma unroll
    for (int s = 0; s < 18; ++s) {
        bf16x8 bt00, bt01, bt10, bt11;
        if (s + 2 < 18) {
            const unsigned short* wt = wB + (s + 2) * 4096;
            bt00 = *reinterpret_cast<const bf16x8*>(wt);
            bt01 = *reinterpret_cast<const bf16x8*>(wt + 16);
            bt10 = *reinterpret_cast<const bf16x8*>(wt + 1024);
            bt11 = *reinterpret_cast<const bf16x8*>(wt + 1040);
        }
        const int dy = s / 6, dx = (s >> 1) % 3, kc = s & 1;
        const unsigned short* arow =
            &A[((wm + dy) * 66 + ln31 + dx) * 72 + kc * 32 + khi * 8];
        bf16x8 a00 = *reinterpret_cast<const bf16x8*>(arow);           // tm0 sk0
        bf16x8 a01 = *reinterpret_cast<const bf16x8*>(arow + 16);      // tm0 sk1
        bf16x8 a10 = *reinterpret_cast<const bf16x8*>(arow + 32 * 72); // tm1 sk0
        bf16x8 a11 = *reinterpret_cast<const bf16x8*>(arow + 32 * 72 + 16);
        __builtin_amdgcn_s_setprio(1);
        acc00 = __builtin_amdgcn_mfma_f32_32x32x16_bf16(a00, bc00, acc00, 0, 0, 0);
        acc01 = __builtin_amdgcn_mfma_f32_32x32x16_bf16(a00, bc10, acc01, 0, 0, 0);
        acc10 = __builtin_amdgcn_mfma_f32_32x32x16_bf16(a10, bc00, acc10, 0, 0, 0);
        acc11 = __builtin_amdgcn_mfma_f32_32x32x16_bf16(a10, bc10, acc11, 0, 0, 0);
        acc00 = __builtin_amdgcn_mfma_f32_32x32x16_bf16(a01, bc01, acc00, 0, 0, 0);
        acc01 = __builtin_amdgcn_mfma_f32_32x32x16_bf16(a01, bc11, acc01, 0, 0, 0);
        acc10 = __builtin_amdgcn_mfma_f32_32x32x16_bf16(a11, bc01, acc10, 0, 0, 0);
        acc11 = __builtin_amdgcn_mfma_f32_32x32x16_bf16(a11, bc11, acc11, 0, 0, 0);
        __builtin_amdgcn_s_setprio(0);
        bc00 = bn00; bc01 = bn01; bc10 = bn10; bc11 = bn11;
        bn00 = bt00; bn01 = bt01; bn10 = bt10; bn11 = bt11;
    }

    // ---- epilogue (barrier-free): NT full-line scalar stores.
    // C/D 32x32: col(n) = lane&31, row(px) = (r&3) + 8*(r>>2) + 4*(lane>>5).
    // For fixed (tn, r): lanes 0-31 write 32 consecutive n = one complete
    // 128B line per store instruction -> NT-safe.
    float* orow = out + ((size_t)(b * 64 + y0 + wm) * 64) * 128;
#pragma unroll
    for (int tm = 0; tm < 2; ++tm) {
#pragma unroll
        for (int tn = 0; tn < 2; ++tn) {
            const f32x16& av = tm == 0 ? (tn == 0 ? acc00 : acc01)
                                       : (tn == 0 ? acc10 : acc11);
            const int n = n0 + tn * 32;
            const float pn = tn == 0 ? pn0 : pn1;
#pragma unroll
            for (int r = 0; r < 16; ++r) {
                const int px = tm * 32 + (r & 3) + 8 * (r >> 2) + 4 * khi;
                float sim = av[r] * xni[wm * 64 + px];
                float aa = fabsf(sim) + 1e-6f;
                float rr = exp2f(pn * log2f(aa));
                __builtin_nontemporal_store(copysignf(rr, sim),
                                            &orow[(size_t)px * 128 + n]);
            }
        }
    }
}

extern "C" void kernel_launch(void* const* d_in, const int* in_sizes, int n_in,
                              void* d_out, int out_size, void* d_ws, size_t ws_size,
                              hipStream_t stream) {
    (void)in_sizes; (void)n_in; (void)out_size; (void)ws_size;
    const float* in = (const float*)d_in[0];
    const float* w  = (const float*)d_in[1];
    const float* p  = (const float*)d_in[2];
    const float* q  = (const float*)d_in[3];
    float* out = (float*)d_out;
    unsigned short* wn = (unsigned short*)d_ws;  // 18*128*32 bf16 = 147456 B

    prep_w_kernel<<<128, 64, 0, stream>>>(w, wn);
    cossim_main<<<1024, 256, 0, stream>>>(in, wn, p, q, out);
}

// Round 19
// 44.689 us; speedup vs baseline: 1.8275x; 1.8275x over previous
//
#include <hip/hip_runtime.h>
#include <hip/hip_bf16.h>

// CosSim2D: inputs (32,64,64,64) f32, w (1,576,128) f32, p (128), q (1)
// out (32,64,64,128) f32.
// R19 = R18 (two-deep B prefetch, setprio cluster, NT line-complete scalar
// epilogue, register p-factors) at __launch_bounds__(256,3): 3 blocks/CU ->
// 170 regs/wave, so the 2-deep pipeline (+32 regs over R17) actually fits
// in the unified VGPR/AGPR file instead of spilling to scratch (R18: 242MB
// write = spill traffic at the 128-reg/wave envelope of (256,4)).

typedef short bf16x8 __attribute__((ext_vector_type(8)));
typedef float f32x16 __attribute__((ext_vector_type(16)));

__device__ __forceinline__ unsigned short f2bf(float f) {
    union { float f; unsigned int u; } v; v.f = f;
    unsigned int u = v.u;
    unsigned int r = (u + 0x7fffu + ((u >> 16) & 1u)) >> 16;  // RNE
    return (unsigned short)r;
}

// ---- pre-kernel: normalize w columns (fp32), store bf16 fragment-contiguous:
// wn2[((tap*2 + kc)*128 + n)*32 + koff] = w_hat[k = tap*64 + kc*32 + koff][n]
__global__ void prep_w_kernel(const float* __restrict__ w,
                              unsigned short* __restrict__ wn2) {
    const int n = blockIdx.x;
    const int lane = threadIdx.x;
    float vals[9];
    float s = 0.f;
#pragma unroll
    for (int i = 0; i < 9; ++i) {
        float v = w[(i * 64 + lane) * 128 + n];
        vals[i] = v;
        s += v * v;
    }
#pragma unroll
    for (int off = 1; off < 64; off <<= 1) s += __shfl_xor(s, off);
    const float inv = 1.0f / sqrtf(fmaxf(s, 1e-12f));
    const int kc = lane >> 5, koff = lane & 31;
#pragma unroll
    for (int i = 0; i < 9; ++i)
        wn2[((i * 2 + kc) * 128 + n) * 32 + koff] = f2bf(vals[i] * inv);
}

// ---- main: one block = (image b, output rows y0,y0+1); 128 pixels x 128 n
__global__ __launch_bounds__(256, 3) void cossim_main(
    const float* __restrict__ in, const unsigned short* __restrict__ wn,
    const float* __restrict__ p, const float* __restrict__ q,
    float* __restrict__ out) {
    // A: [4 rows][66 cols (zero-pad 0,65)][72 ch (64 + 16B pad)] bf16 = 38016 B
    __shared__ unsigned short A[4 * 66 * 72];
    __shared__ float rcsum[256];   // per-(row,col) fp32 square-sums
    __shared__ float xni[128];     // per-pixel 1/(||x||+q_eff)

    const int tid = (int)threadIdx.x;
    // bijective XCD swizzle: 1024 blocks, 8 XCDs, 128 consecutive l per XCD
    const int l = ((int)blockIdx.x & 7) * 128 + ((int)blockIdx.x >> 3);
    const int b = l >> 5, y0 = (l & 31) * 2;

    // ---- stage 4 input rows (y0-1 .. y0+2) + fused fp32 norm partials
    {
        const int r = tid >> 6;        // staged row 0..3
        const int col = tid & 63;
        const int row = y0 + r - 1;
        unsigned short* dst = &A[(r * 66 + col + 1) * 72];
        float s = 0.f;
        if ((unsigned)row < 64u) {
            const float4* src = reinterpret_cast<const float4*>(
                in + (size_t)b * 262144 + row * 4096 + col * 64);
#pragma unroll
            for (int it = 0; it < 8; ++it) {
                float4 v0 = src[2 * it];
                float4 v1 = src[2 * it + 1];
                s += v0.x * v0.x + v0.y * v0.y + v0.z * v0.z + v0.w * v0.w;
                s += v1.x * v1.x + v1.y * v1.y + v1.z * v1.z + v1.w * v1.w;
                union { float f; unsigned u; } ux, uy, uz, uw;
                uint4 pk;
                ux.f = v0.x; uy.f = v0.y; uz.f = v0.z; uw.f = v0.w;
                pk.x = __builtin_amdgcn_perm(uy.u + 0x8000u, ux.u + 0x8000u, 0x07060302u);
                pk.y = __builtin_amdgcn_perm(uw.u + 0x8000u, uz.u + 0x8000u, 0x07060302u);
                ux.f = v1.x; uy.f = v1.y; uz.f = v1.z; uw.f = v1.w;
                pk.z = __builtin_amdgcn_perm(uy.u + 0x8000u, ux.u + 0x8000u, 0x07060302u);
                pk.w = __builtin_amdgcn_perm(uw.u + 0x8000u, uz.u + 0x8000u, 0x07060302u);
                *reinterpret_cast<uint4*>(dst + it * 8) = pk;
            }
        } else {
            uint4 z; z.x = z.y = z.z = z.w = 0u;
#pragma unroll
            for (int it = 0; it < 8; ++it)
                *reinterpret_cast<uint4*>(dst + it * 8) = z;
        }
        rcsum[tid] = s;
    }
    if (tid < 64) {  // zero border cols 0 and 65, all 4 rows
        const int r = tid >> 4, side = (tid >> 3) & 1, ch = (tid & 7) * 8;
        uint4 z; z.x = z.y = z.z = z.w = 0u;
        *reinterpret_cast<uint4*>(&A[(r * 66 + side * 65) * 72 + ch]) = z;
    }
    __syncthreads();

    // ---- per-pixel 1/(||x||+q_eff) from fp32 partials
    if (tid < 128) {
        const int ry = tid >> 6, x = tid & 63;
        const float qe = expf(q[0] * (-1.0f / 0.3f));
        float s = 0.f;
#pragma unroll
        for (int dy = 0; dy < 3; ++dy) {
            const float* rs = &rcsum[(ry + dy) * 64];
            if (x > 0) s += rs[x - 1];
            s += rs[x];
            if (x < 63) s += rs[x + 1];
        }
        xni[tid] = 1.0f / (sqrtf(fmaxf(s, 1e-12f)) + qe);
    }
    __syncthreads();   // xni ready -> epilogue needs NO barrier

    // ---- MFMA loop (32x32x16): wave = output-row wm, 64 px x 64 n (n-half
    // wnh) as 2x2 tiles of 32x32. Per step: 4 A ds_reads + 4 B loads + 8 MFMA.
    // A-frag: row = l&31, k = 8*(l>>5)+j. B-frag: col = l&31, same k.
    const int wv = tid >> 6, lane = tid & 63;
    const int ln31 = lane & 31, khi = lane >> 5;   // khi in {0,1}
    const int wm = wv >> 1, wnh = wv & 1;
    f32x16 acc00 = {}, acc01 = {}, acc10 = {}, acc11 = {};
    const unsigned short* wB = wn + (wnh * 64 + ln31) * 32 + khi * 8;

    // epilogue p-factors hoisted off the post-loop serial path
    const int n0 = wnh * 64 + ln31;
    const float pn0 = expf(p[n0] * 0.2f);
    const float pn1 = expf(p[n0 + 32] * 0.2f);

    // two-deep B pipeline: bc = step s, bn = s+1, bt = s+2 (issued in loop)
    bf16x8 bc00 = *reinterpret_cast<const bf16x8*>(wB);
    bf16x8 bc01 = *reinterpret_cast<const bf16x8*>(wB + 16);
    bf16x8 bc10 = *reinterpret_cast<const bf16x8*>(wB + 1024);
    bf16x8 bc11 = *reinterpret_cast<const bf16x8*>(wB + 1040);
    bf16x8 bn00 = *reinterpret_cast<const bf16x8*>(wB + 4096);
    bf16x8 bn01 = *reinterpret_cast<const bf16x8*>(wB + 4112);
    bf16x8 bn10 = *reinterpret_cast<const bf16x8*>(wB + 5120);
    bf16x8 bn11 = *reinterpret_cast<const bf16x8*>(wB + 5136);

#pragma unroll
    for (int s = 0; s < 18; ++s) {
        bf16x8 bt00, bt01, bt10, bt11;
        if (s + 2 < 18) {
            const unsigned short* wt = wB + (s + 2) * 4096;
            bt00 = *reinterpret_cast<const bf16x8*>(wt);
            bt01 = *reinterpret_cast<const bf16x8*>(wt + 16);
            bt10 = *reinterpret_cast<const bf16x8*>(wt + 1024);
            bt11 = *reinterpret_cast<const bf16x8*>(wt + 1040);
        }
        const int dy = s / 6, dx = (s >> 1) % 3, kc = s & 1;
        const unsigned short* arow =
            &A[((wm + dy) * 66 + ln31 + dx) * 72 + kc * 32 + khi * 8];
        bf16x8 a00 = *reinterpret_cast<const bf16x8*>(arow);           // tm0 sk0
        bf16x8 a01 = *reinterpret_cast<const bf16x8*>(arow + 16);      // tm0 sk1
        bf16x8 a10 = *reinterpret_cast<const bf16x8*>(arow + 32 * 72); // tm1 sk0
        bf16x8 a11 = *reinterpret_cast<const bf16x8*>(arow + 32 * 72 + 16);
        __builtin_amdgcn_s_setprio(1);
        acc00 = __builtin_amdgcn_mfma_f32_32x32x16_bf16(a00, bc00, acc00, 0, 0, 0);
        acc01 = __builtin_amdgcn_mfma_f32_32x32x16_bf16(a00, bc10, acc01, 0, 0, 0);
        acc10 = __builtin_amdgcn_mfma_f32_32x32x16_bf16(a10, bc00, acc10, 0, 0, 0);
        acc11 = __builtin_amdgcn_mfma_f32_32x32x16_bf16(a10, bc10, acc11, 0, 0, 0);
        acc00 = __builtin_amdgcn_mfma_f32_32x32x16_bf16(a01, bc01, acc00, 0, 0, 0);
        acc01 = __builtin_amdgcn_mfma_f32_32x32x16_bf16(a01, bc11, acc01, 0, 0, 0);
        acc10 = __builtin_amdgcn_mfma_f32_32x32x16_bf16(a11, bc01, acc10, 0, 0, 0);
        acc11 = __builtin_amdgcn_mfma_f32_32x32x16_bf16(a11, bc11, acc11, 0, 0, 0);
        __builtin_amdgcn_s_setprio(0);
        bc00 = bn00; bc01 = bn01; bc10 = bn10; bc11 = bn11;
        bn00 = bt00; bn01 = bt01; bn10 = bt10; bn11 = bt11;
    }

    // ---- epilogue (barrier-free): NT full-line scalar stores.
    // C/D 32x32: col(n) = lane&31, row(px) = (r&3) + 8*(r>>2) + 4*(lane>>5).
    // For fixed (tn, r): lanes 0-31 write 32 consecutive n = one complete
    // 128B line per store instruction -> NT-safe.
    float* orow = out + ((size_t)(b * 64 + y0 + wm) * 64) * 128;
#pragma unroll
    for (int tm = 0; tm < 2; ++tm) {
#pragma unroll
        for (int tn = 0; tn < 2; ++tn) {
            const f32x16& av = tm == 0 ? (tn == 0 ? acc00 : acc01)
                                       : (tn == 0 ? acc10 : acc11);
            const int n = n0 + tn * 32;
            const float pn = tn == 0 ? pn0 : pn1;
#pragma unroll
            for (int r = 0; r < 16; ++r) {
                const int px = tm * 32 + (r & 3) + 8 * (r >> 2) + 4 * khi;
                float sim = av[r] * xni[wm * 64 + px];
                float aa = fabsf(sim) + 1e-6f;
                float rr = exp2f(pn * log2f(aa));
                __builtin_nontemporal_store(copysignf(rr, sim),
                                            &orow[(size_t)px * 128 + n]);
            }
        }
    }
}

extern "C" void kernel_launch(void* const* d_in, const int* in_sizes, int n_in,
                              void* d_out, int out_size, void* d_ws, size_t ws_size,
                              hipStream_t stream) {
    (void)in_sizes; (void)n_in; (void)out_size; (void)ws_size;
    const float* in = (const float*)d_in[0];
    const float* w  = (const float*)d_in[1];
    const float* p  = (const float*)d_in[2];
    const float* q  = (const float*)d_in[3];
    float* out = (float*)d_out;
    unsigned short* wn = (unsigned short*)d_ws;  // 18*128*32 bf16 = 147456 B

    prep_w_kernel<<<128, 64, 0, stream>>>(w, wn);
    cossim_main<<<1024, 256, 0, stream>>>(in, wn, p, q, out);
}

// Round 20
// 42.904 us; speedup vs baseline: 1.9035x; 1.0416x over previous
//
#include <hip/hip_runtime.h>
#include <hip/hip_bf16.h>

// CosSim2D: inputs (32,64,64,64) f32, w (1,576,128) f32, p (128), q (1)
// out (32,64,64,128) f32.
// R20 = R17 (best measured: 43.2 us). Final form.
// Structure: one block = (image b, 2 output rows), 1024 blocks, 4 blocks/CU.
// - 32x32x16 MFMA, conflict-free 72-short-padded LDS A-tile (measured 0
//   bank conflicts), fragment-contiguous B (1KB coalesced wave loads),
// - fp32 norm fused into staging (no extra pass),
// - s_setprio(1) around the 8-MFMA cluster (T5; co-resident blocks are
//   phase-diverse since the epilogue is barrier-free),
// - nontemporal LINE-COMPLETE scalar stores (lanes 0-31 = 32 consecutive n
//   = one whole 128B line per store instruction; WRITE = 65536 KB exact),
// - per-lane register p-factors (no pfs LDS pass).
// Ledger: turnover (5 geometries), deeper prefetch (spills at (256,4),
// folds at (256,3)), 2x TLP, B:MFMA ratio changes, MFMA shape - all
// regress or tie. This is the dependency-stall floor of the structure.

typedef short bf16x8 __attribute__((ext_vector_type(8)));
typedef float f32x16 __attribute__((ext_vector_type(16)));

__device__ __forceinline__ unsigned short f2bf(float f) {
    union { float f; unsigned int u; } v; v.f = f;
    unsigned int u = v.u;
    unsigned int r = (u + 0x7fffu + ((u >> 16) & 1u)) >> 16;  // RNE
    return (unsigned short)r;
}

// ---- pre-kernel: normalize w columns (fp32), store bf16 fragment-contiguous:
// wn2[((tap*2 + kc)*128 + n)*32 + koff] = w_hat[k = tap*64 + kc*32 + koff][n]
__global__ void prep_w_kernel(const float* __restrict__ w,
                              unsigned short* __restrict__ wn2) {
    const int n = blockIdx.x;
    const int lane = threadIdx.x;
    float vals[9];
    float s = 0.f;
#pragma unroll
    for (int i = 0; i < 9; ++i) {
        float v = w[(i * 64 + lane) * 128 + n];
        vals[i] = v;
        s += v * v;
    }
#pragma unroll
    for (int off = 1; off < 64; off <<= 1) s += __shfl_xor(s, off);
    const float inv = 1.0f / sqrtf(fmaxf(s, 1e-12f));
    const int kc = lane >> 5, koff = lane & 31;
#pragma unroll
    for (int i = 0; i < 9; ++i)
        wn2[((i * 2 + kc) * 128 + n) * 32 + koff] = f2bf(vals[i] * inv);
}

// ---- main: one block = (image b, output rows y0,y0+1); 128 pixels x 128 n
__global__ __launch_bounds__(256, 4) void cossim_main(
    const float* __restrict__ in, const unsigned short* __restrict__ wn,
    const float* __restrict__ p, const float* __restrict__ q,
    float* __restrict__ out) {
    // A: [4 rows][66 cols (zero-pad 0,65)][72 ch (64 + 16B pad)] bf16 = 38016 B
    __shared__ unsigned short A[4 * 66 * 72];
    __shared__ float rcsum[256];   // per-(row,col) fp32 square-sums
    __shared__ float xni[128];     // per-pixel 1/(||x||+q_eff)

    const int tid = (int)threadIdx.x;
    // bijective XCD swizzle: 1024 blocks, 8 XCDs, 128 consecutive l per XCD
    const int l = ((int)blockIdx.x & 7) * 128 + ((int)blockIdx.x >> 3);
    const int b = l >> 5, y0 = (l & 31) * 2;

    // ---- stage 4 input rows (y0-1 .. y0+2) + fused fp32 norm partials
    {
        const int r = tid >> 6;        // staged row 0..3
        const int col = tid & 63;
        const int row = y0 + r - 1;
        unsigned short* dst = &A[(r * 66 + col + 1) * 72];
        float s = 0.f;
        if ((unsigned)row < 64u) {
            const float4* src = reinterpret_cast<const float4*>(
                in + (size_t)b * 262144 + row * 4096 + col * 64);
#pragma unroll
            for (int it = 0; it < 8; ++it) {
                float4 v0 = src[2 * it];
                float4 v1 = src[2 * it + 1];
                s += v0.x * v0.x + v0.y * v0.y + v0.z * v0.z + v0.w * v0.w;
                s += v1.x * v1.x + v1.y * v1.y + v1.z * v1.z + v1.w * v1.w;
                union { float f; unsigned u; } ux, uy, uz, uw;
                uint4 pk;
                ux.f = v0.x; uy.f = v0.y; uz.f = v0.z; uw.f = v0.w;
                pk.x = __builtin_amdgcn_perm(uy.u + 0x8000u, ux.u + 0x8000u, 0x07060302u);
                pk.y = __builtin_amdgcn_perm(uw.u + 0x8000u, uz.u + 0x8000u, 0x07060302u);
                ux.f = v1.x; uy.f = v1.y; uz.f = v1.z; uw.f = v1.w;
                pk.z = __builtin_amdgcn_perm(uy.u + 0x8000u, ux.u + 0x8000u, 0x07060302u);
                pk.w = __builtin_amdgcn_perm(uw.u + 0x8000u, uz.u + 0x8000u, 0x07060302u);
                *reinterpret_cast<uint4*>(dst + it * 8) = pk;
            }
        } else {
            uint4 z; z.x = z.y = z.z = z.w = 0u;
#pragma unroll
            for (int it = 0; it < 8; ++it)
                *reinterpret_cast<uint4*>(dst + it * 8) = z;
        }
        rcsum[tid] = s;
    }
    if (tid < 64) {  // zero border cols 0 and 65, all 4 rows
        const int r = tid >> 4, side = (tid >> 3) & 1, ch = (tid & 7) * 8;
        uint4 z; z.x = z.y = z.z = z.w = 0u;
        *reinterpret_cast<uint4*>(&A[(r * 66 + side * 65) * 72 + ch]) = z;
    }
    __syncthreads();

    // ---- per-pixel 1/(||x||+q_eff) from fp32 partials
    if (tid < 128) {
        const int ry = tid >> 6, x = tid & 63;
        const float qe = expf(q[0] * (-1.0f / 0.3f));
        float s = 0.f;
#pragma unroll
        for (int dy = 0; dy < 3; ++dy) {
            const float* rs = &rcsum[(ry + dy) * 64];
            if (x > 0) s += rs[x - 1];
            s += rs[x];
            if (x < 63) s += rs[x + 1];
        }
        xni[tid] = 1.0f / (sqrtf(fmaxf(s, 1e-12f)) + qe);
    }
    __syncthreads();   // xni ready -> epilogue needs NO barrier

    // ---- MFMA loop (32x32x16): wave = output-row wm, 64 px x 64 n (n-half
    // wnh) as 2x2 tiles of 32x32. Per step: 4 A ds_reads + 4 B loads + 8 MFMA.
    // A-frag: row = l&31, k = 8*(l>>5)+j. B-frag: col = l&31, same k.
    const int wv = tid >> 6, lane = tid & 63;
    const int ln31 = lane & 31, khi = lane >> 5;   // khi in {0,1}
    const int wm = wv >> 1, wnh = wv & 1;
    f32x16 acc00 = {}, acc01 = {}, acc10 = {}, acc11 = {};
    // B base for this lane: + tn*1024 selects n-tile, + sk*16 selects sub-k
    const unsigned short* wB = wn + (wnh * 64 + ln31) * 32 + khi * 8;

    bf16x8 bc00 = *reinterpret_cast<const bf16x8*>(wB);            // tn0 sk0
    bf16x8 bc01 = *reinterpret_cast<const bf16x8*>(wB + 16);       // tn0 sk1
    bf16x8 bc10 = *reinterpret_cast<const bf16x8*>(wB + 1024);     // tn1 sk0
    bf16x8 bc11 = *reinterpret_cast<const bf16x8*>(wB + 1040);     // tn1 sk1

#pragma unroll
    for (int s = 0; s < 18; ++s) {
        bf16x8 bn00, bn01, bn10, bn11;
        if (s + 1 < 18) {
            const unsigned short* wt = wB + (s + 1) * 4096;
            bn00 = *reinterpret_cast<const bf16x8*>(wt);
            bn01 = *reinterpret_cast<const bf16x8*>(wt + 16);
            bn10 = *reinterpret_cast<const bf16x8*>(wt + 1024);
            bn11 = *reinterpret_cast<const bf16x8*>(wt + 1040);
        }
        const int dy = s / 6, dx = (s >> 1) % 3, kc = s & 1;
        const unsigned short* arow =
            &A[((wm + dy) * 66 + ln31 + dx) * 72 + kc * 32 + khi * 8];
        bf16x8 a00 = *reinterpret_cast<const bf16x8*>(arow);           // tm0 sk0
        bf16x8 a01 = *reinterpret_cast<const bf16x8*>(arow + 16);      // tm0 sk1
        bf16x8 a10 = *reinterpret_cast<const bf16x8*>(arow + 32 * 72); // tm1 sk0
        bf16x8 a11 = *reinterpret_cast<const bf16x8*>(arow + 32 * 72 + 16);
        __builtin_amdgcn_s_setprio(1);
        acc00 = __builtin_amdgcn_mfma_f32_32x32x16_bf16(a00, bc00, acc00, 0, 0, 0);
        acc01 = __builtin_amdgcn_mfma_f32_32x32x16_bf16(a00, bc10, acc01, 0, 0, 0);
        acc10 = __builtin_amdgcn_mfma_f32_32x32x16_bf16(a10, bc00, acc10, 0, 0, 0);
        acc11 = __builtin_amdgcn_mfma_f32_32x32x16_bf16(a10, bc10, acc11, 0, 0, 0);
        acc00 = __builtin_amdgcn_mfma_f32_32x32x16_bf16(a01, bc01, acc00, 0, 0, 0);
        acc01 = __builtin_amdgcn_mfma_f32_32x32x16_bf16(a01, bc11, acc01, 0, 0, 0);
        acc10 = __builtin_amdgcn_mfma_f32_32x32x16_bf16(a11, bc01, acc10, 0, 0, 0);
        acc11 = __builtin_amdgcn_mfma_f32_32x32x16_bf16(a11, bc11, acc11, 0, 0, 0);
        __builtin_amdgcn_s_setprio(0);
        bc00 = bn00; bc01 = bn01; bc10 = bn10; bc11 = bn11;
    }

    // ---- epilogue (barrier-free): per-lane register p-factors, NT stores.
    // C/D 32x32: col(n) = lane&31, row(px) = (r&3) + 8*(r>>2) + 4*(lane>>5).
    // For fixed (tn, r): lanes 0-31 write 32 consecutive n = one complete
    // 128B line per store instruction -> NT-safe (no partial lines).
    const int n0 = wnh * 64 + ln31;
    const float pn0 = expf(p[n0] * 0.2f);
    const float pn1 = expf(p[n0 + 32] * 0.2f);
    float* orow = out + ((size_t)(b * 64 + y0 + wm) * 64) * 128;
#pragma unroll
    for (int tm = 0; tm < 2; ++tm) {
#pragma unroll
        for (int tn = 0; tn < 2; ++tn) {
            const f32x16& av = tm == 0 ? (tn == 0 ? acc00 : acc01)
                                       : (tn == 0 ? acc10 : acc11);
            const int n = n0 + tn * 32;
            const float pn = tn == 0 ? pn0 : pn1;
#pragma unroll
            for (int r = 0; r < 16; ++r) {
                const int px = tm * 32 + (r & 3) + 8 * (r >> 2) + 4 * khi;
                float sim = av[r] * xni[wm * 64 + px];
                float aa = fabsf(sim) + 1e-6f;
                float rr = exp2f(pn * log2f(aa));
                __builtin_nontemporal_store(copysignf(rr, sim),
                                            &orow[(size_t)px * 128 + n]);
            }
        }
    }
}

extern "C" void kernel_launch(void* const* d_in, const int* in_sizes, int n_in,
                              void* d_out, int out_size, void* d_ws, size_t ws_size,
                              hipStream_t stream) {
    (void)in_sizes; (void)n_in; (void)out_size; (void)ws_size;
    const float* in = (const float*)d_in[0];
    const float* w  = (const float*)d_in[1];
    const float* p  = (const float*)d_in[2];
    const float* q  = (const float*)d_in[3];
    float* out = (float*)d_out;
    unsigned short* wn = (unsigned short*)d_ws;  // 18*128*32 bf16 = 147456 B

    prep_w_kernel<<<128, 64, 0, stream>>>(w, wn);
    cossim_main<<<1024, 256, 0, stream>>>(in, wn, p, q, out);
}